// Round 1
// baseline (4760.215 us; speedup 1.0000x reference)
//
#include <hip/hip_runtime.h>

#define Cn 16
#define Bn 128
#define Hn 40
#define Wn 40
#define Sn 32
#define HID 128
#define PIX (Bn * Hn * Wn)          // 204800
#define NFRAME (Sn + 1)             // 33
#define RGB_TOTAL (NFRAME * PIX * 3)
#define STACK_FRAME (PIX * Cn)
#define ALPHA_T 0.1f

// ---------------------------------------------------------------------------
// Kernel A: per-pixel perception + MLP, produces pre-mask state P
//   P = S + upd_mask * (W2 @ relu(W1 @ perception + b1))
// ---------------------------------------------------------------------------
__global__ __launch_bounds__(256) void step_update(
    const float* __restrict__ S,      // [PIX*16] current (already-masked) state
    const int*   __restrict__ maskT,  // [PIX] update mask for this step
    float*       __restrict__ P,      // [PIX*16] out: pre-mask new state
    const float* __restrict__ W1,     // [128*48]
    const float* __restrict__ b1,     // [128]
    const float* __restrict__ W2)     // [16*128]
{
    int idx = blockIdx.x * 256 + threadIdx.x;
    if (idx >= PIX) return;
    int x  = idx % Wn;
    int t1 = idx / Wn;
    int y  = t1 % Hn;
    int b  = t1 / Hn;

    // ---- alive mask of the 3x3 neighborhood (needs alpha in radius 2) ----
    float alpha[5][5];
#pragma unroll
    for (int dy = 0; dy < 5; ++dy) {
#pragma unroll
        for (int dx = 0; dx < 5; ++dx) {
            int yy = y + dy - 2, xx = x + dx - 2;
            bool in = (yy >= 0) && (yy < Hn) && (xx >= 0) && (xx < Wn);
            alpha[dy][dx] = in ? S[(((b * Hn + yy) * Wn) + xx) * Cn + 3] : -1e30f;
        }
    }
    float am[3][3];
#pragma unroll
    for (int dy = 0; dy < 3; ++dy) {
#pragma unroll
        for (int dx = 0; dx < 3; ++dx) {
            float p = alpha[dy][dx];
            p = fmaxf(p, alpha[dy][dx + 1]);
            p = fmaxf(p, alpha[dy][dx + 2]);
            p = fmaxf(p, alpha[dy + 1][dx]);
            p = fmaxf(p, alpha[dy + 1][dx + 1]);
            p = fmaxf(p, alpha[dy + 1][dx + 2]);
            p = fmaxf(p, alpha[dy + 2][dx]);
            p = fmaxf(p, alpha[dy + 2][dx + 1]);
            p = fmaxf(p, alpha[dy + 2][dx + 2]);
            am[dy][dx] = (p >= ALPHA_T) ? 1.0f : 0.0f;
        }
    }

    // ---- perception: [masked(16) | sobel_x(16) | sobel_y(16)] ----
    float perc[48];
#pragma unroll
    for (int cg = 0; cg < 4; ++cg) {
        float4 m[3][3];
#pragma unroll
        for (int dy = 0; dy < 3; ++dy) {
#pragma unroll
            for (int dx = 0; dx < 3; ++dx) {
                int yy = y + dy - 1, xx = x + dx - 1;
                bool in = (yy >= 0) && (yy < Hn) && (xx >= 0) && (xx < Wn);
                float4 v;
                if (in) {
                    v = *(const float4*)&S[((((b * Hn + yy) * Wn) + xx) * Cn) + cg * 4];
                    float a = am[dy][dx];
                    v.x *= a; v.y *= a; v.z *= a; v.w *= a;
                } else {
                    v.x = 0.f; v.y = 0.f; v.z = 0.f; v.w = 0.f;
                }
                m[dy][dx] = v;
            }
        }
        // masked center
        perc[cg * 4 + 0] = m[1][1].x;
        perc[cg * 4 + 1] = m[1][1].y;
        perc[cg * 4 + 2] = m[1][1].z;
        perc[cg * 4 + 3] = m[1][1].w;
        // sobel x: (m[.][2]-m[.][0]) weights 1,2,1 over rows, /8
        perc[16 + cg * 4 + 0] = ((m[0][2].x - m[0][0].x) + 2.f * (m[1][2].x - m[1][0].x) + (m[2][2].x - m[2][0].x)) * 0.125f;
        perc[16 + cg * 4 + 1] = ((m[0][2].y - m[0][0].y) + 2.f * (m[1][2].y - m[1][0].y) + (m[2][2].y - m[2][0].y)) * 0.125f;
        perc[16 + cg * 4 + 2] = ((m[0][2].z - m[0][0].z) + 2.f * (m[1][2].z - m[1][0].z) + (m[2][2].z - m[2][0].z)) * 0.125f;
        perc[16 + cg * 4 + 3] = ((m[0][2].w - m[0][0].w) + 2.f * (m[1][2].w - m[1][0].w) + (m[2][2].w - m[2][0].w)) * 0.125f;
        // sobel y: (m[2][.]-m[0][.]) weights 1,2,1 over cols, /8
        perc[32 + cg * 4 + 0] = ((m[2][0].x - m[0][0].x) + 2.f * (m[2][1].x - m[0][1].x) + (m[2][2].x - m[0][2].x)) * 0.125f;
        perc[32 + cg * 4 + 1] = ((m[2][0].y - m[0][0].y) + 2.f * (m[2][1].y - m[0][1].y) + (m[2][2].y - m[0][2].y)) * 0.125f;
        perc[32 + cg * 4 + 2] = ((m[2][0].z - m[0][0].z) + 2.f * (m[2][1].z - m[0][1].z) + (m[2][2].z - m[0][2].z)) * 0.125f;
        perc[32 + cg * 4 + 3] = ((m[2][0].w - m[0][0].w) + 2.f * (m[2][1].w - m[0][1].w) + (m[2][2].w - m[0][2].w)) * 0.125f;
    }

    // ---- MLP: hid = relu(W1 @ perc + b1); upd = W2 @ hid ----
    float upd[16];
#pragma unroll
    for (int c = 0; c < 16; ++c) upd[c] = 0.f;

    for (int j = 0; j < HID; ++j) {
        float h = b1[j];
        const float* w1row = &W1[j * 48];
#pragma unroll
        for (int i = 0; i < 48; ++i) h = fmaf(perc[i], w1row[i], h);
        h = fmaxf(h, 0.f);
#pragma unroll
        for (int c = 0; c < 16; ++c) upd[c] = fmaf(h, W2[c * HID + j], upd[c]);
    }

    float fm = (float)maskT[idx];

#pragma unroll
    for (int cg = 0; cg < 4; ++cg) {
        float4 s = *(const float4*)&S[idx * Cn + cg * 4];
        float4 o;
        o.x = s.x + upd[cg * 4 + 0] * fm;
        o.y = s.y + upd[cg * 4 + 1] * fm;
        o.z = s.z + upd[cg * 4 + 2] * fm;
        o.w = s.w + upd[cg * 4 + 3] * fm;
        *(float4*)&P[idx * Cn + cg * 4] = o;
    }
}

// ---------------------------------------------------------------------------
// Kernel B: S_next = P * alive_mask(P)
// ---------------------------------------------------------------------------
__global__ __launch_bounds__(256) void step_mask(
    const float* __restrict__ P,
    float*       __restrict__ Snext)
{
    int idx = blockIdx.x * 256 + threadIdx.x;
    if (idx >= PIX) return;
    int x  = idx % Wn;
    int t1 = idx / Wn;
    int y  = t1 % Hn;
    int b  = t1 / Hn;

    float pooled = -1e30f;
#pragma unroll
    for (int dy = -1; dy <= 1; ++dy) {
#pragma unroll
        for (int dx = -1; dx <= 1; ++dx) {
            int yy = y + dy, xx = x + dx;
            bool in = (yy >= 0) && (yy < Hn) && (xx >= 0) && (xx < Wn);
            if (in) pooled = fmaxf(pooled, P[(((b * Hn + yy) * Wn) + xx) * Cn + 3]);
        }
    }
    float am = (pooled >= ALPHA_T) ? 1.0f : 0.0f;

#pragma unroll
    for (int cg = 0; cg < 4; ++cg) {
        float4 v = *(const float4*)&P[idx * Cn + cg * 4];
        v.x *= am; v.y *= am; v.z *= am; v.w *= am;
        *(float4*)&Snext[idx * Cn + cg * 4] = v;
    }
}

// ---------------------------------------------------------------------------
// Init copy: stacked[0] = initial_state
// ---------------------------------------------------------------------------
__global__ __launch_bounds__(256) void copy_init(
    const float4* __restrict__ src, float4* __restrict__ dst, int n4)
{
    int i = blockIdx.x * 256 + threadIdx.x;
    if (i < n4) dst[i] = src[i];
}

// ---------------------------------------------------------------------------
// RGB: rgb = trunc(clip(1 - clip(a,0,1) + rgb_ch, 0, 1) * 255), stored as f32
// ---------------------------------------------------------------------------
__global__ __launch_bounds__(256) void rgb_kernel(
    const float* __restrict__ stacked, float* __restrict__ rgb, int npix)
{
    int idx = blockIdx.x * 256 + threadIdx.x;
    if (idx >= npix) return;
    float4 s = *(const float4*)&stacked[idx * Cn];
    float a = fminf(fmaxf(s.w, 0.f), 1.f);
    float base = 1.f - a;
    rgb[idx * 3 + 0] = truncf(fminf(fmaxf(base + s.x, 0.f), 1.f) * 255.f);
    rgb[idx * 3 + 1] = truncf(fminf(fmaxf(base + s.y, 0.f), 1.f) * 255.f);
    rgb[idx * 3 + 2] = truncf(fminf(fmaxf(base + s.z, 0.f), 1.f) * 255.f);
}

extern "C" void kernel_launch(void* const* d_in, const int* in_sizes, int n_in,
                              void* d_out, int out_size, void* d_ws, size_t ws_size,
                              hipStream_t stream) {
    const float* init = (const float*)d_in[0];
    const float* W1   = (const float*)d_in[1];
    const float* b1   = (const float*)d_in[2];
    const float* W2   = (const float*)d_in[3];
    const int*   upd  = (const int*)d_in[4];

    float* out     = (float*)d_out;
    float* rgb     = out;                 // [NFRAME*PIX*3]
    float* stacked = out + RGB_TOTAL;     // [NFRAME*PIX*16]
    // Transient pre-mask state buffer: stage it in the rgb region (written
    // last), so we make no assumption about ws_size. Needs PIX*16 floats
    // (3.28M) <= RGB_TOTAL (20.3M). OK.
    float* P = out;

    const int blocks_pix = (PIX + 255) / 256;

    copy_init<<<(PIX * Cn / 4 + 255) / 256, 256, 0, stream>>>(
        (const float4*)init, (float4*)stacked, PIX * Cn / 4);

    for (int t = 0; t < Sn; ++t) {
        step_update<<<blocks_pix, 256, 0, stream>>>(
            stacked + (size_t)t * STACK_FRAME, upd + (size_t)t * PIX, P, W1, b1, W2);
        step_mask<<<blocks_pix, 256, 0, stream>>>(
            P, stacked + (size_t)(t + 1) * STACK_FRAME);
    }

    const int npix_all = NFRAME * PIX;
    rgb_kernel<<<(npix_all + 255) / 256, 256, 0, stream>>>(stacked, rgb, npix_all);
}